// Round 2
// baseline (259.350 us; speedup 1.0000x reference)
//
#include <hip/hip_runtime.h>
#include <hip/hip_bf16.h>

typedef __bf16 bf16;
typedef __bf16 bf16x4 __attribute__((ext_vector_type(4)));
typedef __bf16 bf16x8 __attribute__((ext_vector_type(8)));
typedef float floatx4 __attribute__((ext_vector_type(4)));

#define D_MODEL 512
#define NHEAD 8
#define HD 64
#define NB 2
#define NN 2048
#define BH (NB*NHEAD)

// ---------------- kernel 0: mask fp32 -> bf16 ----------------
__global__ __launch_bounds__(256) void maskconv(const float* __restrict__ m,
                                                bf16* __restrict__ mb) {
    int idx = (blockIdx.x * 256 + threadIdx.x) * 4;
    float4 v = *(const float4*)(m + idx);
    bf16x4 o; o[0] = (bf16)v.x; o[1] = (bf16)v.y; o[2] = (bf16)v.z; o[3] = (bf16)v.w;
    *(bf16x4*)(mb + idx) = o;
}

// ---------------- kernel 1: coord projection cp[b,h,n] = coords[b,n,:]·rw[h,:] ----------------
__global__ __launch_bounds__(256) void coordproj(const float* __restrict__ coords,
                                                 const float* __restrict__ rw,
                                                 float* __restrict__ cp) {
    int idx = blockIdx.x * 256 + threadIdx.x;      // 0..4095 over (b,n)
    int b = idx >> 11, n = idx & 2047;
    float c0 = coords[idx*3 + 0];
    float c1 = coords[idx*3 + 1];
    float c2 = coords[idx*3 + 2];
    for (int h = 0; h < NHEAD; h++) {
        float v = c0*rw[h*3+0] + c1*rw[h*3+1] + c2*rw[h*3+2];
        cp[(size_t)(b*NHEAD + h)*NN + n] = v;
    }
}

// ---------------- kernel 2: QKV GEMM: out[r][c] = sum_k x[r][k]*W[c][k] + b[c] ----------------
// M=4096 (b,n), N=1536 (mat,h,d), K=512. Tile 128x128x64, 256 threads (4 waves, 2x2).
// fp32 inputs converted to bf16 at LDS staging. Epilogue: Q*0.125 -> qb[bh][n][d];
// K -> kb[bh][n][d]; V -> vtb[bh][d][n] (transposed).
__global__ __launch_bounds__(256) void qkv_gemm(const float* __restrict__ x,
                                                const float* __restrict__ w,
                                                const float* __restrict__ bias,
                                                bf16* __restrict__ qb,
                                                bf16* __restrict__ kb,
                                                bf16* __restrict__ vtb) {
    __shared__ bf16 As[128][72];
    __shared__ bf16 Bs[128][72];
    int t = threadIdx.x;
    int wave = t >> 6, lane = t & 63;
    int quad = lane >> 4, l15 = lane & 15;
    int wr = wave >> 1, wc = wave & 1;
    int blk = blockIdx.x;
    int bn = blk % 12, bm = blk / 12;
    int m0 = bm * 128, n0 = bn * 128;

    floatx4 acc[4][4] = {};

    int sr = t >> 4;            // 0..15 (16 rows per sweep)
    int sc = (t & 15) * 4;      // 4-float chunks

    for (int k0 = 0; k0 < D_MODEL; k0 += 64) {
        __syncthreads();
        for (int i = 0; i < 8; i++) {
            int r = i*16 + sr;
            float4 xv = *(const float4*)(x + (size_t)(m0 + r)*D_MODEL + k0 + sc);
            bf16x4 xb; xb[0] = (bf16)xv.x; xb[1] = (bf16)xv.y; xb[2] = (bf16)xv.z; xb[3] = (bf16)xv.w;
            *(bf16x4*)&As[r][sc] = xb;
            float4 wv = *(const float4*)(w + (size_t)(n0 + r)*D_MODEL + k0 + sc);
            bf16x4 wb; wb[0] = (bf16)wv.x; wb[1] = (bf16)wv.y; wb[2] = (bf16)wv.z; wb[3] = (bf16)wv.w;
            *(bf16x4*)&Bs[r][sc] = wb;
        }
        __syncthreads();
        for (int kk = 0; kk < 64; kk += 32) {
            bf16x8 af[4], bfv[4];
            for (int i = 0; i < 4; i++)
                af[i] = *(const bf16x8*)&As[wr*64 + i*16 + l15][kk + quad*8];
            for (int j = 0; j < 4; j++)
                bfv[j] = *(const bf16x8*)&Bs[wc*64 + j*16 + l15][kk + quad*8];
            for (int i = 0; i < 4; i++)
                for (int j = 0; j < 4; j++)
                    acc[i][j] = __builtin_amdgcn_mfma_f32_16x16x32_bf16(af[i], bfv[j], acc[i][j], 0, 0, 0);
        }
    }

    for (int j = 0; j < 4; j++) {
        int c = n0 + wc*64 + j*16 + l15;       // output feature
        float bv = bias[c];
        int mat = c >> 9;                       // 0=q 1=k 2=v (uniform per frag)
        int rem = c & 511;
        int h = rem >> 6, d = rem & 63;
        for (int i = 0; i < 4; i++) {
            for (int r = 0; r < 4; r++) {
                int m = m0 + wr*64 + i*16 + quad*4 + r;
                int bb = m >> 11, n = m & 2047;
                float v = acc[i][j][r] + bv;
                size_t bho = (size_t)(bb*NHEAD + h);
                if (mat == 0)      qb[(bho*NN + n)*HD + d] = (bf16)(v * 0.125f);
                else if (mat == 1) kb[(bho*NN + n)*HD + d] = (bf16)v;
                else               vtb[(bho*HD + d)*NN + n] = (bf16)v;
            }
        }
    }
}

// ---------------- kernel 3: flash attention ----------------
// grid: 512 blocks = bh*32 + qtile  (qtile of 64 q-rows). 256 threads, 4 waves; wave owns 16 q-rows.
// Loop key tiles of 128: S = Q*K^T (pre-scaled Q) + mask - cp[k]; online softmax; O += P*V.
// (+cp[q] is constant per softmax row -> cancels; dropped.)
__global__ __launch_bounds__(256) void attn(const bf16* __restrict__ qb,
                                            const bf16* __restrict__ kb,
                                            const bf16* __restrict__ vtb,
                                            const bf16* __restrict__ mask,
                                            const float* __restrict__ cp,
                                            float* __restrict__ out) {
    __shared__ bf16 Ks[128][72];    // keys x dims
    __shared__ bf16 Vts[64][136];   // dims x keys
    __shared__ bf16 Ps[64][136];    // qrows x keys
    int t = threadIdx.x;
    int w = t >> 6, lane = t & 63;
    int quad = lane >> 4, l15 = lane & 15;
    int blk = blockIdx.x;
    int bh = blk >> 5;              // 0..15
    int qt = blk & 31;              // 0..31
    int q0 = qt * 64;
    size_t bhoff = (size_t)bh * (NN * HD);

    // Q fragments (A-operand): rows q0+w*16+l15, k = kf*32 + quad*8
    bf16x8 aq[2];
    {
        const bf16* qp = qb + bhoff + (size_t)(q0 + w*16 + l15)*HD + quad*8;
        aq[0] = *(const bf16x8*)(qp);
        aq[1] = *(const bf16x8*)(qp + 32);
    }

    float m_i[4], l_i[4];
    floatx4 o[4] = {};
    for (int r = 0; r < 4; r++) { m_i[r] = -1e30f; l_i[r] = 0.f; }

    const float* cpb = cp + (size_t)bh * NN;
    int mrow_base = q0 + w*16 + quad*4;

    int sr = t >> 4, sc = (t & 15) * 4;     // K staging: 16 thr/row
    int vr = t >> 5, vc = (t & 31) * 4;     // Vt staging: 32 thr/row

    for (int kt = 0; kt < NN / 128; kt++) {
        int k0 = kt * 128;
        __syncthreads();
        {
            const bf16* ksrc = kb + bhoff + (size_t)(k0 + sr)*HD + sc;
            for (int i = 0; i < 8; i++)
                *(bf16x4*)&Ks[i*16 + sr][sc] = *(const bf16x4*)(ksrc + (size_t)i*16*HD);
            const bf16* vsrc = vtb + bhoff + (size_t)vr*NN + k0 + vc;
            for (int i = 0; i < 8; i++)
                *(bf16x4*)&Vts[i*8 + vr][vc] = *(const bf16x4*)(vsrc + (size_t)i*8*NN);
        }
        __syncthreads();

        // S = Q*K^T  (16 q-rows x 128 keys per wave)
        floatx4 s[8] = {};
        for (int kf = 0; kf < 2; kf++) {
            for (int j = 0; j < 8; j++) {
                bf16x8 bk = *(const bf16x8*)&Ks[j*16 + l15][kf*32 + quad*8];
                s[j] = __builtin_amdgcn_mfma_f32_16x16x32_bf16(aq[kf], bk, s[j], 0, 0, 0);
            }
        }

        // bias: + mask[q][k] - cp[k]
        float cpv[8];
        for (int j = 0; j < 8; j++) cpv[j] = cpb[k0 + j*16 + l15];
        const bf16* mrow = mask + (size_t)mrow_base*NN + k0 + l15;
        for (int j = 0; j < 8; j++)
            for (int r = 0; r < 4; r++)
                s[j][r] += (float)mrow[(size_t)r*NN + j*16] - cpv[j];

        // row max over 128 keys (16-lane groups share a q-row set)
        float mx[4];
        for (int r = 0; r < 4; r++) {
            float v = s[0][r];
            for (int j = 1; j < 8; j++) v = fmaxf(v, s[j][r]);
            for (int off = 1; off < 16; off <<= 1) v = fmaxf(v, __shfl_xor(v, off));
            mx[r] = v;
        }
        float al[4], rs[4];
        for (int r = 0; r < 4; r++) {
            float mn = fmaxf(m_i[r], mx[r]);
            al[r] = __expf(m_i[r] - mn);
            m_i[r] = mn;
            rs[r] = 0.f;
        }
        for (int j = 0; j < 8; j++)
            for (int r = 0; r < 4; r++) {
                float p = __expf(s[j][r] - m_i[r]);
                s[j][r] = p;
                rs[r] += p;
            }
        for (int r = 0; r < 4; r++) {
            for (int off = 1; off < 16; off <<= 1) rs[r] += __shfl_xor(rs[r], off);
            l_i[r] = l_i[r]*al[r] + rs[r];
        }
        for (int dj = 0; dj < 4; dj++)
            for (int r = 0; r < 4; r++) o[dj][r] *= al[r];

        // P -> LDS (C-layout -> A-layout round trip; same-wave rows only, in-order LDS)
        int prow = w*16 + quad*4;
        for (int j = 0; j < 8; j++)
            for (int r = 0; r < 4; r++)
                Ps[prow + r][j*16 + l15] = (bf16)s[j][r];

        // O += P * V   (A = P rows, B = Vt rows)
        for (int kf2 = 0; kf2 < 4; kf2++) {
            bf16x8 ap = *(const bf16x8*)&Ps[w*16 + l15][kf2*32 + quad*8];
            for (int dj = 0; dj < 4; dj++) {
                bf16x8 bv = *(const bf16x8*)&Vts[dj*16 + l15][kf2*32 + quad*8];
                o[dj] = __builtin_amdgcn_mfma_f32_16x16x32_bf16(ap, bv, o[dj], 0, 0, 0);
            }
        }
    }

    // epilogue: out[b][n][h*64+d] = O / l   (fp32 output)
    int b = bh >> 3, h = bh & 7;
    float inv[4];
    for (int r = 0; r < 4; r++) inv[r] = 1.0f / l_i[r];
    for (int dj = 0; dj < 4; dj++) {
        for (int r = 0; r < 4; r++) {
            int n = q0 + w*16 + quad*4 + r;
            float v = o[dj][r] * inv[r];
            out[((size_t)(b*NN + n))*D_MODEL + h*HD + dj*16 + l15] = v;
        }
    }
}

extern "C" void kernel_launch(void* const* d_in, const int* in_sizes, int n_in,
                              void* d_out, int out_size, void* d_ws, size_t ws_size,
                              hipStream_t stream) {
    const float* x      = (const float*)d_in[0];
    const float* coords = (const float*)d_in[1];
    const float* amask  = (const float*)d_in[2];
    const float* qkv_w  = (const float*)d_in[3];
    const float* qkv_b  = (const float*)d_in[4];
    const float* rw     = (const float*)d_in[5];
    float* out = (float*)d_out;

    // workspace layout (bytes)
    float* cp   = (float*)d_ws;                                  // 131072 B
    bf16*  mb   = (bf16*)((char*)d_ws + 131072);                 // 8 MB  mask bf16
    bf16*  qb   = (bf16*)((char*)d_ws + 131072 + 8388608);       // 4 MB
    bf16*  kb   = qb + (size_t)BH*NN*HD;                         // 4 MB
    bf16*  vtb  = kb + (size_t)BH*NN*HD;                         // 4 MB (transposed V)

    maskconv <<<dim3(4096), dim3(256), 0, stream>>>(amask, mb);
    coordproj<<<dim3(16),   dim3(256), 0, stream>>>(coords, rw, cp);
    qkv_gemm <<<dim3(384),  dim3(256), 0, stream>>>(x, qkv_w, qkv_b, qb, kb, vtb);
    attn     <<<dim3(512),  dim3(256), 0, stream>>>(qb, kb, vtb, mb, cp, out);
}

// Round 3
// 175.778 us; speedup vs baseline: 1.4754x; 1.4754x over previous
//
#include <hip/hip_runtime.h>
#include <hip/hip_bf16.h>

typedef __bf16 bf16;
typedef __bf16 bf16x4 __attribute__((ext_vector_type(4)));
typedef __bf16 bf16x8 __attribute__((ext_vector_type(8)));
typedef float floatx4 __attribute__((ext_vector_type(4)));

#define D_MODEL 512
#define NHEAD 8
#define HD 64
#define NB 2
#define NN 2048
#define BH (NB*NHEAD)

// ---------------- kernel 0: convert x and w fp32 -> bf16 ----------------
// x: 2097152 el (524288 float4), w: 786432 el (196608 float4). grid 2816*256.
__global__ __launch_bounds__(256) void convxw(const float* __restrict__ x,
                                              const float* __restrict__ w,
                                              bf16* __restrict__ xb,
                                              bf16* __restrict__ wb) {
    int idx = blockIdx.x * 256 + threadIdx.x;
    const float* src; bf16* dst; int i4;
    if (idx < 524288) { src = x; dst = xb; i4 = idx; }
    else              { src = w; dst = wb; i4 = idx - 524288; }
    float4 v = *(const float4*)(src + (size_t)i4*4);
    bf16x4 o; o[0] = (bf16)v.x; o[1] = (bf16)v.y; o[2] = (bf16)v.z; o[3] = (bf16)v.w;
    *(bf16x4*)(dst + (size_t)i4*4) = o;
}

// ---------------- kernel 1: coord projection cp[b,h,n] ----------------
__global__ __launch_bounds__(256) void coordproj(const float* __restrict__ coords,
                                                 const float* __restrict__ rw,
                                                 float* __restrict__ cp) {
    int idx = blockIdx.x * 256 + threadIdx.x;      // 0..4095 over (b,n)
    int b = idx >> 11, n = idx & 2047;
    float c0 = coords[idx*3 + 0];
    float c1 = coords[idx*3 + 1];
    float c2 = coords[idx*3 + 2];
    for (int h = 0; h < NHEAD; h++) {
        float v = c0*rw[h*3+0] + c1*rw[h*3+1] + c2*rw[h*3+2];
        cp[(size_t)(b*NHEAD + h)*NN + n] = v;
    }
}

// ---------------- kernel 2: QKV GEMM (bf16 in), 64x64 tiles, 1536 blocks ----------------
__global__ __launch_bounds__(256) void qkv_gemm(const bf16* __restrict__ xb,
                                                const bf16* __restrict__ wb,
                                                const float* __restrict__ bias,
                                                bf16* __restrict__ qb,
                                                bf16* __restrict__ kb,
                                                bf16* __restrict__ vtb) {
    __shared__ bf16 As[64][72];
    __shared__ bf16 Bs[64][72];
    int t = threadIdx.x;
    int w = t >> 6, lane = t & 63;
    int quad = lane >> 4, l15 = lane & 15;
    int blk = blockIdx.x;
    int bn = blk % 24, bm = blk / 24;
    int m0 = bm * 64, n0 = bn * 64;
    int srow = t >> 2, scol = (t & 3) * 16;

    floatx4 acc[4] = {};

    for (int k0 = 0; k0 < D_MODEL; k0 += 64) {
        __syncthreads();
        {
            const bf16* xs = xb + (size_t)(m0 + srow)*D_MODEL + k0 + scol;
            *(bf16x8*)&As[srow][scol]     = *(const bf16x8*)xs;
            *(bf16x8*)&As[srow][scol + 8] = *(const bf16x8*)(xs + 8);
            const bf16* ws = wb + (size_t)(n0 + srow)*D_MODEL + k0 + scol;
            *(bf16x8*)&Bs[srow][scol]     = *(const bf16x8*)ws;
            *(bf16x8*)&Bs[srow][scol + 8] = *(const bf16x8*)(ws + 8);
        }
        __syncthreads();
        for (int kf = 0; kf < 2; kf++) {
            bf16x8 af = *(const bf16x8*)&As[w*16 + l15][kf*32 + quad*8];
            for (int j = 0; j < 4; j++) {
                bf16x8 bfv = *(const bf16x8*)&Bs[j*16 + l15][kf*32 + quad*8];
                acc[j] = __builtin_amdgcn_mfma_f32_16x16x32_bf16(af, bfv, acc[j], 0, 0, 0);
            }
        }
    }

    for (int j = 0; j < 4; j++) {
        int c = n0 + j*16 + l15;               // output feature
        float bv = bias[c];
        int mat = c >> 9;                       // 0=q 1=k 2=v
        int rem = c & 511;
        int h = rem >> 6, d = rem & 63;
        for (int r = 0; r < 4; r++) {
            int m = m0 + w*16 + quad*4 + r;
            int bb = m >> 11, n = m & 2047;
            float v = acc[j][r] + bv;
            size_t bho = (size_t)(bb*NHEAD + h);
            if (mat == 0)      qb[(bho*NN + n)*HD + d] = (bf16)(v * 0.125f);
            else if (mat == 1) kb[(bho*NN + n)*HD + d] = (bf16)v;
            else               vtb[(bho*HD + d)*NN + n] = (bf16)v;
        }
    }
}

// ---------------- kernel 3: flash attention, S^T formulation ----------------
// grid = 16 bh * 32 qt * ksplit. 256 thr / 4 waves; wave owns 16 q-rows (q = l15 in T-layout).
// Key tiles of 64. S^T = K*Q^T (A=K,B=Q) -> lane holds P^T[key=j*16+quad*4+r][q=l15]:
// row-softmax = in-lane tree + 2 shfl_xor; mask/cp loads are contiguous float4;
// P write to LDS is ds_write_b64. PV in original orientation (A=P, B=Vt).
__global__ __launch_bounds__(256, 4) void attn(const bf16* __restrict__ qb,
                                               const bf16* __restrict__ kb,
                                               const bf16* __restrict__ vtb,
                                               const float* __restrict__ maskf,
                                               const float* __restrict__ cp,
                                               float* __restrict__ op,
                                               float* __restrict__ ml,
                                               float* __restrict__ out,
                                               int ksplit) {
    __shared__ bf16 Ks[64][72];
    __shared__ bf16 Vts[64][72];
    __shared__ bf16 Ps[64][72];
    int t = threadIdx.x;
    int w = t >> 6, lane = t & 63;
    int quad = lane >> 4, l15 = lane & 15;
    int blk = blockIdx.x;
    int bh = blk & 15;
    int rest = blk >> 4;
    int qt = rest & 31, kp = rest >> 5;
    int q0 = qt * 64;
    int nkeys = NN / ksplit;
    int kbase = kp * nkeys;
    size_t bhoff = (size_t)bh * (NN * HD);

    // Q fragment (B-operand; same reg layout as A): q = q0 + w*16 + l15
    bf16x8 aq0, aq1;
    {
        const bf16* qp = qb + bhoff + (size_t)(q0 + w*16 + l15)*HD + quad*8;
        aq0 = *(const bf16x8*)(qp);
        aq1 = *(const bf16x8*)(qp + 32);
    }

    float m_i = -1e30f, l_i = 0.f;
    floatx4 o[4] = {};
    int qrow = q0 + w*16 + l15;
    const float* mrow = maskf + (size_t)qrow * NN;
    const float* cpb = cp + (size_t)bh * NN;
    int srow = t >> 2, scol = (t & 3) * 16;

    for (int kt = 0; kt < nkeys/64; kt++) {
        int k0 = kbase + kt*64;
        __syncthreads();
        {
            const bf16* ks = kb + bhoff + (size_t)(k0 + srow)*HD + scol;
            *(bf16x8*)&Ks[srow][scol]     = *(const bf16x8*)ks;
            *(bf16x8*)&Ks[srow][scol + 8] = *(const bf16x8*)(ks + 8);
            const bf16* vs = vtb + bhoff + (size_t)srow*NN + k0 + scol;
            *(bf16x8*)&Vts[srow][scol]     = *(const bf16x8*)vs;
            *(bf16x8*)&Vts[srow][scol + 8] = *(const bf16x8*)(vs + 8);
        }
        __syncthreads();

        // S^T: lane -> P^T[key=j*16+quad*4+r][q=l15]
        floatx4 s[4] = {};
        for (int j = 0; j < 4; j++) {
            bf16x8 ka0 = *(const bf16x8*)&Ks[j*16 + l15][quad*8];
            bf16x8 ka1 = *(const bf16x8*)&Ks[j*16 + l15][32 + quad*8];
            s[j] = __builtin_amdgcn_mfma_f32_16x16x32_bf16(ka0, aq0, s[j], 0, 0, 0);
            s[j] = __builtin_amdgcn_mfma_f32_16x16x32_bf16(ka1, aq1, s[j], 0, 0, 0);
        }

        // bias: + mask[q][key] - cp[key]  (contiguous per lane)
        for (int j = 0; j < 4; j++) {
            float4 mv = *(const float4*)(mrow + k0 + j*16 + quad*4);
            float4 cv = *(const float4*)(cpb + k0 + j*16 + quad*4);
            s[j][0] += mv.x - cv.x;
            s[j][1] += mv.y - cv.y;
            s[j][2] += mv.z - cv.z;
            s[j][3] += mv.w - cv.w;
        }

        // row softmax for q=l15: in-lane over 16 + xor16/32 across quads
        float mx = s[0][0];
        for (int j = 0; j < 4; j++)
            for (int r = 0; r < 4; r++) mx = fmaxf(mx, s[j][r]);
        mx = fmaxf(mx, __shfl_xor(mx, 16));
        mx = fmaxf(mx, __shfl_xor(mx, 32));
        float mnew = fmaxf(m_i, mx);
        float al = __expf(m_i - mnew);
        float rs = 0.f;
        for (int j = 0; j < 4; j++)
            for (int r = 0; r < 4; r++) {
                float p = __expf(s[j][r] - mnew);
                s[j][r] = p;
                rs += p;
            }
        rs += __shfl_xor(rs, 16);
        rs += __shfl_xor(rs, 32);
        l_i = l_i * al + rs;
        m_i = mnew;

        // rescale O (C-orientation: row q = quad*4+r) -> transpose al via 4 shfl
        float alc[4];
        for (int r = 0; r < 4; r++) alc[r] = __shfl(al, quad*4 + r);
        for (int dj = 0; dj < 4; dj++)
            for (int r = 0; r < 4; r++) o[dj][r] *= alc[r];

        // P^T -> Ps[q][key] as b64 vector writes (same-wave rows; no barrier needed)
        for (int j = 0; j < 4; j++) {
            bf16x4 pv;
            pv[0] = (bf16)s[j][0]; pv[1] = (bf16)s[j][1];
            pv[2] = (bf16)s[j][2]; pv[3] = (bf16)s[j][3];
            *(bf16x4*)&Ps[w*16 + l15][j*16 + quad*4] = pv;
        }

        // O += P*V  (A=P rows, B=Vt rows) -> O[q=quad*4+r][d=dj*16+l15]
        for (int kf2 = 0; kf2 < 2; kf2++) {
            bf16x8 ap = *(const bf16x8*)&Ps[w*16 + l15][kf2*32 + quad*8];
            for (int dj = 0; dj < 4; dj++) {
                bf16x8 bv = *(const bf16x8*)&Vts[dj*16 + l15][kf2*32 + quad*8];
                o[dj] = __builtin_amdgcn_mfma_f32_16x16x32_bf16(ap, bv, o[dj], 0, 0, 0);
            }
        }
    }

    int b = bh >> 3, h = bh & 7;
    if (ksplit == 1) {
        float lc[4];
        for (int r = 0; r < 4; r++) lc[r] = __shfl(l_i, quad*4 + r);
        for (int dj = 0; dj < 4; dj++) {
            for (int r = 0; r < 4; r++) {
                int n = q0 + w*16 + quad*4 + r;
                out[((size_t)(b*NN + n))*D_MODEL + h*HD + dj*16 + l15] = o[dj][r] / lc[r];
            }
        }
    } else {
        size_t pbase = (size_t)kp * BH * NN;
        for (int dj = 0; dj < 4; dj++) {
            for (int r = 0; r < 4; r++) {
                int n = q0 + w*16 + quad*4 + r;
                op[(pbase + bh*NN + n)*HD + dj*16 + l15] = o[dj][r];
            }
        }
        if (quad == 0) {
            float2 v; v.x = m_i; v.y = l_i;
            *(float2*)(ml + (pbase + (size_t)bh*NN + qrow)*2) = v;
        }
    }
}

// ---------------- kernel 4: combine 2 k-split partials ----------------
__global__ __launch_bounds__(256) void combine2(const float* __restrict__ op,
                                                const float* __restrict__ ml,
                                                float* __restrict__ out) {
    int idx = blockIdx.x * 256 + threadIdx.x;    // 524288 = 32768 rows * 16 chunks
    int row = idx >> 4, c4 = (idx & 15) * 4;
    float2 ml0 = *(const float2*)(ml + (size_t)row*2);
    float2 ml1 = *(const float2*)(ml + ((size_t)BH*NN + row)*2);
    float mstar = fmaxf(ml0.x, ml1.x);
    float w0 = __expf(ml0.x - mstar);
    float w1 = __expf(ml1.x - mstar);
    float inv = 1.0f / (w0*ml0.y + w1*ml1.y);
    float4 o0 = *(const float4*)(op + (size_t)row*HD + c4);
    float4 o1 = *(const float4*)(op + ((size_t)BH*NN + row)*HD + c4);
    float4 res;
    res.x = (w0*o0.x + w1*o1.x) * inv;
    res.y = (w0*o0.y + w1*o1.y) * inv;
    res.z = (w0*o0.z + w1*o1.z) * inv;
    res.w = (w0*o0.w + w1*o1.w) * inv;
    int bh = row >> 11, q = row & 2047;
    int b = bh >> 3, h = bh & 7;
    *(float4*)(out + ((size_t)(b*NN + q))*D_MODEL + h*HD + c4) = res;
}

extern "C" void kernel_launch(void* const* d_in, const int* in_sizes, int n_in,
                              void* d_out, int out_size, void* d_ws, size_t ws_size,
                              hipStream_t stream) {
    const float* x      = (const float*)d_in[0];
    const float* coords = (const float*)d_in[1];
    const float* amask  = (const float*)d_in[2];
    const float* qkv_w  = (const float*)d_in[3];
    const float* qkv_b  = (const float*)d_in[4];
    const float* rw     = (const float*)d_in[5];
    float* out = (float*)d_out;

    // workspace layout (byte offsets)
    char* ws = (char*)d_ws;
    float* cp  = (float*)(ws + 0);          // 131072
    bf16*  xb  = (bf16*) (ws + 131072);     // 4194304
    bf16*  wb  = (bf16*) (ws + 4325376);    // 1572864
    bf16*  qb  = (bf16*) (ws + 5898240);    // 4194304
    bf16*  kb  = (bf16*) (ws + 10092544);   // 4194304
    bf16*  vtb = (bf16*) (ws + 14286848);   // 4194304
    float* op  = (float*)(ws + 18481152);   // 16777216
    float* ml  = (float*)(ws + 35258368);   // 524288  -> total 35782656

    int split = (ws_size >= 35782656u) ? 2 : 1;

    convxw   <<<dim3(2816), dim3(256), 0, stream>>>(x, qkv_w, xb, wb);
    coordproj<<<dim3(16),   dim3(256), 0, stream>>>(coords, rw, cp);
    qkv_gemm <<<dim3(1536), dim3(256), 0, stream>>>(xb, wb, qkv_b, qb, kb, vtb);
    attn     <<<dim3(512*split), dim3(256), 0, stream>>>(qb, kb, vtb, amask, cp, op, ml, out, split);
    if (split == 2)
        combine2<<<dim3(2048), dim3(256), 0, stream>>>(op, ml, out);
}

// Round 4
// 152.471 us; speedup vs baseline: 1.7010x; 1.1529x over previous
//
#include <hip/hip_runtime.h>
#include <hip/hip_bf16.h>

typedef __bf16 bf16;
typedef __bf16 bf16x4 __attribute__((ext_vector_type(4)));
typedef __bf16 bf16x8 __attribute__((ext_vector_type(8)));
typedef float floatx4 __attribute__((ext_vector_type(4)));

#define D_MODEL 512
#define NHEAD 8
#define HD 64
#define NB 2
#define NN 2048
#define BH (NB*NHEAD)

// ---------------- kernel 0: convert x and w fp32 -> bf16 ----------------
__global__ __launch_bounds__(256) void convxw(const float* __restrict__ x,
                                              const float* __restrict__ w,
                                              bf16* __restrict__ xb,
                                              bf16* __restrict__ wb) {
    int idx = blockIdx.x * 256 + threadIdx.x;
    const float* src; bf16* dst; int i4;
    if (idx < 524288) { src = x; dst = xb; i4 = idx; }
    else              { src = w; dst = wb; i4 = idx - 524288; }
    float4 v = *(const float4*)(src + (size_t)i4*4);
    bf16x4 o; o[0] = (bf16)v.x; o[1] = (bf16)v.y; o[2] = (bf16)v.z; o[3] = (bf16)v.w;
    *(bf16x4*)(dst + (size_t)i4*4) = o;
}

// ---------------- kernel 1: coord projection cp[b,h,n] ----------------
__global__ __launch_bounds__(256) void coordproj(const float* __restrict__ coords,
                                                 const float* __restrict__ rw,
                                                 float* __restrict__ cp) {
    int idx = blockIdx.x * 256 + threadIdx.x;
    int b = idx >> 11, n = idx & 2047;
    float c0 = coords[idx*3 + 0];
    float c1 = coords[idx*3 + 1];
    float c2 = coords[idx*3 + 2];
    for (int h = 0; h < NHEAD; h++) {
        float v = c0*rw[h*3+0] + c1*rw[h*3+1] + c2*rw[h*3+2];
        cp[(size_t)(b*NHEAD + h)*NN + n] = v;
    }
}

// ---------------- kernel 2: QKV GEMM, C^T = W * X^T ----------------
// Tile: 64 features x 128 rows, K=512. 768 blocks, 256 thr / 4 waves.
// Wave w owns rows [w*32,w*32+32) x all 64 features: 16 MFMA per k-iter.
// mat/h uniform per block. Q/K: b64 vector stores. V: LDS transpose -> coalesced b128.
__global__ __launch_bounds__(256, 4) void qkv_gemm(const bf16* __restrict__ xb,
                                                   const bf16* __restrict__ wb,
                                                   const float* __restrict__ bias,
                                                   bf16* __restrict__ qb,
                                                   bf16* __restrict__ kb,
                                                   bf16* __restrict__ vtb) {
    __shared__ bf16 smem[64*72 + 128*72];
    bf16 (*Ws)[72] = (bf16(*)[72])smem;
    bf16 (*Xs)[72] = (bf16(*)[72])(smem + 64*72);
    int t = threadIdx.x;
    int w = t >> 6, lane = t & 63, quad = lane >> 4, l15 = lane & 15;
    int blk = blockIdx.x;
    int bf = blk % 24, bm = blk / 24;
    int f0 = bf * 64, m0 = bm * 128;

    floatx4 acc[4][2] = {};
    int wrow = t >> 2, wcol = (t & 3) * 16;
    int xrow = t >> 1, xcol = (t & 1) * 32;

    for (int k0 = 0; k0 < D_MODEL; k0 += 64) {
        __syncthreads();
        {
            const bf16* wsrc = wb + (size_t)(f0 + wrow)*D_MODEL + k0 + wcol;
            *(bf16x8*)&Ws[wrow][wcol]   = *(const bf16x8*)wsrc;
            *(bf16x8*)&Ws[wrow][wcol+8] = *(const bf16x8*)(wsrc + 8);
            const bf16* xsrc = xb + (size_t)(m0 + xrow)*D_MODEL + k0 + xcol;
            *(bf16x8*)&Xs[xrow][xcol]    = *(const bf16x8*)xsrc;
            *(bf16x8*)&Xs[xrow][xcol+8]  = *(const bf16x8*)(xsrc + 8);
            *(bf16x8*)&Xs[xrow][xcol+16] = *(const bf16x8*)(xsrc + 16);
            *(bf16x8*)&Xs[xrow][xcol+24] = *(const bf16x8*)(xsrc + 24);
        }
        __syncthreads();
        for (int kf = 0; kf < 2; kf++) {
            bf16x8 af[4], bx[2];
            for (int fi = 0; fi < 4; fi++)
                af[fi] = *(const bf16x8*)&Ws[fi*16 + l15][kf*32 + quad*8];
            for (int mj = 0; mj < 2; mj++)
                bx[mj] = *(const bf16x8*)&Xs[w*32 + mj*16 + l15][kf*32 + quad*8];
            for (int fi = 0; fi < 4; fi++)
                for (int mj = 0; mj < 2; mj++)
                    acc[fi][mj] = __builtin_amdgcn_mfma_f32_16x16x32_bf16(af[fi], bx[mj], acc[fi][mj], 0, 0, 0);
        }
    }

    // lane holds C^T[f = f0 + fi*16 + quad*4 + r][m = m0 + w*32 + mj*16 + l15]
    int mat = f0 >> 9;                 // uniform per block
    int h = (f0 >> 6) & 7;             // uniform
    int b = m0 >> 11;                  // uniform
    int nb = m0 & 2047;
    size_t bho = (size_t)(b*NHEAD + h);
    float4 bs4[4];
    for (int fi = 0; fi < 4; fi++)
        bs4[fi] = *(const float4*)(bias + f0 + fi*16 + quad*4);

    if (mat < 2) {
        bf16* dst = (mat == 0) ? qb : kb;
        float sc = (mat == 0) ? 0.125f : 1.0f;
        for (int fi = 0; fi < 4; fi++) {
            for (int mj = 0; mj < 2; mj++) {
                int n = nb + w*32 + mj*16 + l15;
                bf16x4 pv;
                pv[0] = (bf16)((acc[fi][mj][0] + bs4[fi].x) * sc);
                pv[1] = (bf16)((acc[fi][mj][1] + bs4[fi].y) * sc);
                pv[2] = (bf16)((acc[fi][mj][2] + bs4[fi].z) * sc);
                pv[3] = (bf16)((acc[fi][mj][3] + bs4[fi].w) * sc);
                *(bf16x4*)(dst + (bho*NN + n)*HD + fi*16 + quad*4) = pv;
            }
        }
    } else {
        __syncthreads();                       // all k-loop LDS reads done
        bf16* Vt = smem;                       // [64][136]
        for (int fi = 0; fi < 4; fi++) {
            int d = fi*16 + quad*4;
            for (int mj = 0; mj < 2; mj++) {
                int mlc = w*32 + mj*16 + l15;
                Vt[(d+0)*136 + mlc] = (bf16)(acc[fi][mj][0] + bs4[fi].x);
                Vt[(d+1)*136 + mlc] = (bf16)(acc[fi][mj][1] + bs4[fi].y);
                Vt[(d+2)*136 + mlc] = (bf16)(acc[fi][mj][2] + bs4[fi].z);
                Vt[(d+3)*136 + mlc] = (bf16)(acc[fi][mj][3] + bs4[fi].w);
            }
        }
        __syncthreads();
        int d = t >> 2, mc = (t & 3) * 32;
        bf16* gdst = vtb + (bho*HD + d)*NN + nb + mc;
        for (int c = 0; c < 4; c++)
            *(bf16x8*)(gdst + c*8) = *(const bf16x8*)&Vt[d*136 + mc + c*8];
    }
}

// ---------------- kernel 3: flash attention, S^T + register prefetch ----------------
__global__ __launch_bounds__(256, 4) void attn(const bf16* __restrict__ qb,
                                               const bf16* __restrict__ kb,
                                               const bf16* __restrict__ vtb,
                                               const float* __restrict__ maskf,
                                               const float* __restrict__ cp,
                                               float* __restrict__ op,
                                               float* __restrict__ ml,
                                               float* __restrict__ out,
                                               int ksplit) {
    __shared__ bf16 Ks[64][72];
    __shared__ bf16 Vts[64][72];
    __shared__ bf16 Ps[64][72];
    __shared__ float Cs[2048];
    int t = threadIdx.x;
    int w = t >> 6, lane = t & 63;
    int quad = lane >> 4, l15 = lane & 15;
    int blk = blockIdx.x;
    int bh = blk & 15;
    int rest = blk >> 4;
    int qt = rest & 31, kp = rest >> 5;
    int q0 = qt * 64;
    int nkeys = NN / ksplit;
    int ntiles = nkeys / 64;
    int kbase = kp * nkeys;
    size_t bhoff = (size_t)bh * (NN * HD);

    bf16x8 aq0, aq1;
    {
        const bf16* qp = qb + bhoff + (size_t)(q0 + w*16 + l15)*HD + quad*8;
        aq0 = *(const bf16x8*)(qp);
        aq1 = *(const bf16x8*)(qp + 32);
    }

    float m_i = -1e30f, l_i = 0.f;
    floatx4 o[4] = {};
    int qrow = q0 + w*16 + l15;
    const float* mrow = maskf + (size_t)qrow * NN;
    const float* cpb = cp + (size_t)bh * NN;
    int srow = t >> 2, scol = (t & 3) * 16;

    // stage cp slice once
    for (int i = t; i < nkeys; i += 256) Cs[i] = cpb[kbase + i];
    __syncthreads();

    // prefetch tile 0
    bf16x8 kr0, kr1, vr0, vr1;
    float4 bias4[4];
    {
        const bf16* ks = kb + bhoff + (size_t)(kbase + srow)*HD + scol;
        kr0 = *(const bf16x8*)ks; kr1 = *(const bf16x8*)(ks + 8);
        const bf16* vs = vtb + bhoff + (size_t)srow*NN + kbase + scol;
        vr0 = *(const bf16x8*)vs; vr1 = *(const bf16x8*)(vs + 8);
        for (int j = 0; j < 4; j++) {
            float4 mv = *(const float4*)(mrow + kbase + j*16 + quad*4);
            float4 cv = *(const float4*)&Cs[j*16 + quad*4];
            bias4[j].x = mv.x - cv.x; bias4[j].y = mv.y - cv.y;
            bias4[j].z = mv.z - cv.z; bias4[j].w = mv.w - cv.w;
        }
    }

    for (int kt = 0; kt < ntiles; kt++) {
        __syncthreads();
        *(bf16x8*)&Ks[srow][scol]      = kr0;
        *(bf16x8*)&Ks[srow][scol + 8]  = kr1;
        *(bf16x8*)&Vts[srow][scol]     = vr0;
        *(bf16x8*)&Vts[srow][scol + 8] = vr1;
        __syncthreads();

        // prefetch next tile (global loads overlap compute below)
        float4 mn4[4];
        bool more = (kt + 1 < ntiles);
        if (more) {
            int kn = kbase + (kt+1)*64;
            const bf16* ks = kb + bhoff + (size_t)(kn + srow)*HD + scol;
            kr0 = *(const bf16x8*)ks; kr1 = *(const bf16x8*)(ks + 8);
            const bf16* vs = vtb + bhoff + (size_t)srow*NN + kn + scol;
            vr0 = *(const bf16x8*)vs; vr1 = *(const bf16x8*)(vs + 8);
            for (int j = 0; j < 4; j++)
                mn4[j] = *(const float4*)(mrow + kn + j*16 + quad*4);
        }

        // S^T = K*Q^T + (mask - cp), via accumulator init
        floatx4 s[4];
        for (int j = 0; j < 4; j++) {
            s[j][0] = bias4[j].x; s[j][1] = bias4[j].y;
            s[j][2] = bias4[j].z; s[j][3] = bias4[j].w;
            bf16x8 ka0 = *(const bf16x8*)&Ks[j*16 + l15][quad*8];
            bf16x8 ka1 = *(const bf16x8*)&Ks[j*16 + l15][32 + quad*8];
            s[j] = __builtin_amdgcn_mfma_f32_16x16x32_bf16(ka0, aq0, s[j], 0, 0, 0);
            s[j] = __builtin_amdgcn_mfma_f32_16x16x32_bf16(ka1, aq1, s[j], 0, 0, 0);
        }

        // softmax for q=l15: in-lane tree + 2 shfl
        float mx = s[0][0];
        for (int j = 0; j < 4; j++)
            for (int r = 0; r < 4; r++) mx = fmaxf(mx, s[j][r]);
        mx = fmaxf(mx, __shfl_xor(mx, 16));
        mx = fmaxf(mx, __shfl_xor(mx, 32));
        float mnew = fmaxf(m_i, mx);
        float al = __expf(m_i - mnew);
        float rs = 0.f;
        for (int j = 0; j < 4; j++)
            for (int r = 0; r < 4; r++) {
                float p = __expf(s[j][r] - mnew);
                s[j][r] = p;
                rs += p;
            }
        rs += __shfl_xor(rs, 16);
        rs += __shfl_xor(rs, 32);
        l_i = l_i * al + rs;
        m_i = mnew;

        float alc[4];
        for (int r = 0; r < 4; r++) alc[r] = __shfl(al, quad*4 + r);
        for (int dj = 0; dj < 4; dj++)
            for (int r = 0; r < 4; r++) o[dj][r] *= alc[r];

        // P^T -> Ps (b64 writes; same-wave rows, in-order LDS)
        for (int j = 0; j < 4; j++) {
            bf16x4 pv;
            pv[0] = (bf16)s[j][0]; pv[1] = (bf16)s[j][1];
            pv[2] = (bf16)s[j][2]; pv[3] = (bf16)s[j][3];
            *(bf16x4*)&Ps[w*16 + l15][j*16 + quad*4] = pv;
        }

        // O += P*V
        for (int kf2 = 0; kf2 < 2; kf2++) {
            bf16x8 ap = *(const bf16x8*)&Ps[w*16 + l15][kf2*32 + quad*8];
            for (int dj = 0; dj < 4; dj++) {
                bf16x8 bv = *(const bf16x8*)&Vts[dj*16 + l15][kf2*32 + quad*8];
                o[dj] = __builtin_amdgcn_mfma_f32_16x16x32_bf16(ap, bv, o[dj], 0, 0, 0);
            }
        }

        // rotate next-tile bias
        if (more) {
            int kn_loc = (kt+1)*64;
            for (int j = 0; j < 4; j++) {
                float4 cv = *(const float4*)&Cs[kn_loc + j*16 + quad*4];
                bias4[j].x = mn4[j].x - cv.x; bias4[j].y = mn4[j].y - cv.y;
                bias4[j].z = mn4[j].z - cv.z; bias4[j].w = mn4[j].w - cv.w;
            }
        }
    }

    int b = bh >> 3, h = bh & 7;
    if (ksplit == 1) {
        float lc[4];
        for (int r = 0; r < 4; r++) lc[r] = __shfl(l_i, quad*4 + r);
        for (int dj = 0; dj < 4; dj++) {
            for (int r = 0; r < 4; r++) {
                int n = q0 + w*16 + quad*4 + r;
                out[((size_t)(b*NN + n))*D_MODEL + h*HD + dj*16 + l15] = o[dj][r] / lc[r];
            }
        }
    } else {
        size_t pbase = (size_t)kp * BH * NN;
        for (int dj = 0; dj < 4; dj++) {
            for (int r = 0; r < 4; r++) {
                int n = q0 + w*16 + quad*4 + r;
                op[(pbase + bh*NN + n)*HD + dj*16 + l15] = o[dj][r];
            }
        }
        if (quad == 0) {
            float2 v; v.x = m_i; v.y = l_i;
            *(float2*)(ml + (pbase + (size_t)bh*NN + qrow)*2) = v;
        }
    }
}

// ---------------- kernel 4: combine ksplit partials ----------------
__global__ __launch_bounds__(256) void combineN(const float* __restrict__ op,
                                                const float* __restrict__ ml,
                                                float* __restrict__ out,
                                                int ksplit) {
    int idx = blockIdx.x * 256 + threadIdx.x;    // 32768 rows * 16 chunks
    int row = idx >> 4, c4 = (idx & 15) * 4;
    float mstar = -1e30f;
    for (int kp = 0; kp < ksplit; kp++)
        mstar = fmaxf(mstar, ml[((size_t)kp*BH*NN + row)*2]);
    float denom = 0.f;
    float ax = 0.f, ay = 0.f, az = 0.f, aw = 0.f;
    for (int kp = 0; kp < ksplit; kp++) {
        float2 m2 = *(const float2*)(ml + ((size_t)kp*BH*NN + row)*2);
        float wgt = __expf(m2.x - mstar);
        denom += wgt * m2.y;
        float4 ov = *(const float4*)(op + ((size_t)kp*BH*NN + row)*HD + c4);
        ax += wgt*ov.x; ay += wgt*ov.y; az += wgt*ov.z; aw += wgt*ov.w;
    }
    float inv = 1.0f / denom;
    int bh = row >> 11, q = row & 2047;
    int b = bh >> 3, h = bh & 7;
    float4 res; res.x = ax*inv; res.y = ay*inv; res.z = az*inv; res.w = aw*inv;
    *(float4*)(out + ((size_t)(b*NN + q))*D_MODEL + h*HD + c4) = res;
}

extern "C" void kernel_launch(void* const* d_in, const int* in_sizes, int n_in,
                              void* d_out, int out_size, void* d_ws, size_t ws_size,
                              hipStream_t stream) {
    const float* x      = (const float*)d_in[0];
    const float* coords = (const float*)d_in[1];
    const float* amask  = (const float*)d_in[2];
    const float* qkv_w  = (const float*)d_in[3];
    const float* qkv_b  = (const float*)d_in[4];
    const float* rw     = (const float*)d_in[5];
    float* out = (float*)d_out;

    char* ws = (char*)d_ws;
    float* cp  = (float*)(ws + 0);          // 131072
    bf16*  xb  = (bf16*) (ws + 131072);     // 4194304
    bf16*  wb  = (bf16*) (ws + 4325376);    // 1572864
    bf16*  qb  = (bf16*) (ws + 5898240);    // 4194304
    bf16*  kb  = (bf16*) (ws + 10092544);   // 4194304
    bf16*  vtb = (bf16*) (ws + 14286848);   // 4194304
    float* op  = (float*)(ws + 18481152);   // split*8388608

    int split = 1;
    if (ws_size >= 53084160u)      split = 4;
    else if (ws_size >= 35782656u) split = 2;
    float* ml = (float*)(ws + 18481152 + (size_t)split*8388608);

    convxw   <<<dim3(2816), dim3(256), 0, stream>>>(x, qkv_w, xb, wb);
    coordproj<<<dim3(16),   dim3(256), 0, stream>>>(coords, rw, cp);
    qkv_gemm <<<dim3(768),  dim3(256), 0, stream>>>(xb, wb, qkv_b, qb, kb, vtb);
    attn     <<<dim3(512*split), dim3(256), 0, stream>>>(qb, kb, vtb, amask, cp, op, ml, out, split);
    if (split > 1)
        combineN<<<dim3(2048), dim3(256), 0, stream>>>(op, ml, out, split);
}